// Round 2
// baseline (801.948 us; speedup 1.0000x reference)
//
#include <hip/hip_runtime.h>
#include <hip/hip_bf16.h>

#define BATCH 2
#define SEQ   2048
#define HID   2048
#define NH    16
#define NKV   8
#define HD    128

typedef __bf16 bf16;
typedef bf16  bf16x8  __attribute__((ext_vector_type(8)));
typedef float floatx4 __attribute__((ext_vector_type(4)));

// load 8 contiguous f32 and round to bf16x8 (compiler emits 2x dwordx4)
__device__ inline bf16x8 cvt8_f32(const float* p) {
    bf16x8 r;
    #pragma unroll
    for (int i = 0; i < 8; i++) r[i] = (bf16)p[i];
    return r;
}

// ---------------------------------------------------------------------------
// GEMM: C[M,N] = A[M,K] * W[N,K]^T   (fp32 accum, bf16 MFMA)
// TA: dtype of A in global (float or bf16). W is always float. TC: C dtype.
// 64x64 tile, BK=32, 4 waves, each wave 32x32 (2x2 mfma 16x16x32 bf16).
// LDS rows padded to 40 bf16 (80 B: 16B-aligned, 2-way banks -> free).
// ---------------------------------------------------------------------------
template <typename TA, typename TC>
__global__ __launch_bounds__(256) void gemm_bt(TC* __restrict__ C,
                                               const TA* __restrict__ A,
                                               const float* __restrict__ W,
                                               int M, int N, int K)
{
    __shared__ bf16 As[64 * 40];
    __shared__ bf16 Ws[64 * 40];

    const int tid  = threadIdx.x;
    const int wave = tid >> 6;
    const int lane = tid & 63;
    const int quad = lane >> 4;
    const int c16  = lane & 15;

    const int m0 = blockIdx.x * 64;
    const int n0 = blockIdx.y * 64;
    const int wm = (wave >> 1) * 32;
    const int wn = (wave & 1) * 32;

    // staging: each thread covers 8 elements of a 64x32 tile of A and W
    const int sr = tid >> 2;         // 0..63
    const int sc = (tid & 3) * 8;    // 0,8,16,24

    floatx4 acc[2][2] = {};

    for (int k0 = 0; k0 < K; k0 += 32) {
        bf16x8 av;
        if constexpr (__is_same(TA, float)) {
            av = cvt8_f32(A + (size_t)(m0 + sr) * K + k0 + sc);
        } else {
            av = *(const bf16x8*)(A + (size_t)(m0 + sr) * K + k0 + sc);
        }
        bf16x8 wv = cvt8_f32(W + (size_t)(n0 + sr) * K + k0 + sc);
        *(bf16x8*)(&As[sr * 40 + sc]) = av;
        *(bf16x8*)(&Ws[sr * 40 + sc]) = wv;
        __syncthreads();

        bf16x8 a0 = *(const bf16x8*)(&As[(wm + c16) * 40 + quad * 8]);
        bf16x8 a1 = *(const bf16x8*)(&As[(wm + 16 + c16) * 40 + quad * 8]);
        bf16x8 b0 = *(const bf16x8*)(&Ws[(wn + c16) * 40 + quad * 8]);
        bf16x8 b1 = *(const bf16x8*)(&Ws[(wn + 16 + c16) * 40 + quad * 8]);

        acc[0][0] = __builtin_amdgcn_mfma_f32_16x16x32_bf16(a0, b0, acc[0][0], 0, 0, 0);
        acc[0][1] = __builtin_amdgcn_mfma_f32_16x16x32_bf16(a0, b1, acc[0][1], 0, 0, 0);
        acc[1][0] = __builtin_amdgcn_mfma_f32_16x16x32_bf16(a1, b0, acc[1][0], 0, 0, 0);
        acc[1][1] = __builtin_amdgcn_mfma_f32_16x16x32_bf16(a1, b1, acc[1][1], 0, 0, 0);
        __syncthreads();
    }

    // C/D layout: col = lane&15, row = quad*4 + reg  [verified m89/m91]
    #pragma unroll
    for (int i = 0; i < 2; i++)
        #pragma unroll
        for (int j = 0; j < 2; j++)
            #pragma unroll
            for (int r = 0; r < 4; r++) {
                int m = m0 + wm + i * 16 + quad * 4 + r;
                int n = n0 + wn + j * 16 + c16;
                C[(size_t)m * N + n] = (TC)acc[i][j][r];
            }
}

// ---------------------------------------------------------------------------
// Fused per-head RMSNorm (over D=128) + RoPE, in place on bf16 q/k buffers.
// pe and norm weights are fp32 inputs. grid = (SEQ, NH+NKV, BATCH), block=128
// ---------------------------------------------------------------------------
__global__ __launch_bounds__(128) void norm_rope(bf16* __restrict__ q,
                                                 bf16* __restrict__ k,
                                                 const float* __restrict__ pe,
                                                 const float* __restrict__ qnw,
                                                 const float* __restrict__ knw)
{
    const int s  = blockIdx.x;
    const int hh = blockIdx.y;
    const int b  = blockIdx.z;
    const int d  = threadIdx.x;

    bf16* buf;
    const float* w;
    if (hh < NH) {
        buf = q + ((size_t)(b * SEQ + s) * NH + hh) * HD;
        w = qnw;
    } else {
        buf = k + ((size_t)(b * SEQ + s) * NKV + (hh - NH)) * HD;
        w = knw;
    }

    float x = (float)buf[d];
    float ss = x * x;
    #pragma unroll
    for (int m = 32; m; m >>= 1) ss += __shfl_xor(ss, m);

    __shared__ float red[2];
    __shared__ float nv[128];
    if ((d & 63) == 0) red[d >> 6] = ss;
    __syncthreads();
    float var = (red[0] + red[1]) * (1.0f / 128.0f);
    float nx = x * rsqrtf(var + 1e-6f) * w[d];
    nv[d] = nx;
    __syncthreads();

    const float* pev = pe + ((size_t)b * SEQ + s) * HD;
    float o;
    if (d < 64) {
        o = nx * pev[d] - nv[d + 64] * pev[64 + d];        // x1*cos - x2*sin
    } else {
        o = nv[d - 64] * pev[d] + nx * pev[d - 64];        // x1*sin + x2*cos
    }
    buf[d] = (bf16)o;
}

// ---------------------------------------------------------------------------
// Flash attention (causal, GQA rep=2). block = 4 waves = 64 queries of one
// (b,h). Per 32-key tile: K staged [32][136], V staged transposed [128][40].
// QK^T: 8 mfma; online softmax (quad-local shfl_xor row reductions);
// P -> LDS -> A-layout; PV: 8 mfma.  All bf16 workspace tensors.
// ---------------------------------------------------------------------------
__global__ __launch_bounds__(256) void fattn(bf16* __restrict__ O,
                                             const bf16* __restrict__ Q,
                                             const bf16* __restrict__ K,
                                             const bf16* __restrict__ V)
{
    const int qblk = blockIdx.x;
    const int h    = blockIdx.y;
    const int b    = blockIdx.z;
    const int kv   = h >> 1;            // GQA: rep = 2

    const int tid  = threadIdx.x;
    const int wave = tid >> 6;
    const int lane = tid & 63;
    const int quad = lane >> 4;
    const int c    = lane & 15;

    __shared__ bf16 Ks[32 * 136];       // [key][d]
    __shared__ bf16 Vt[128 * 40];       // [d][key]
    __shared__ bf16 Ps[4 * 16 * 40];    // per-wave P tile [16][40]

    const int qw = qblk * 64 + wave * 16;   // wave's first query row

    // Q fragments: A[m=lane&15][k=quad*8+j], k-offsets t*32
    bf16x8 qf[4];
    const bf16* qptr = Q + ((size_t)(b * SEQ + qw + c) * NH + h) * HD + quad * 8;
    #pragma unroll
    for (int t = 0; t < 4; t++) qf[t] = *(const bf16x8*)(qptr + t * 32);

    floatx4 o_acc[8] = {};
    float m_r[4], l_r[4];
    #pragma unroll
    for (int r = 0; r < 4; r++) { m_r[r] = -INFINITY; l_r[r] = 0.0f; }

    const int nkt  = qblk * 2 + 2;      // key tiles covering keys <= qblk*64+63
    const int krow = tid >> 3;          // 0..31
    const int kcol = (tid & 7) * 16;    // 0..112
    bf16* psw = &Ps[wave * 16 * 40];
    const float scale = 0.08838834764831845f;  // 1/sqrt(128)

    for (int kt = 0; kt < nkt; kt++) {
        const int k0 = kt * 32;
        // ---- stage K tile and transposed V tile ----
        {
            const bf16* kptr = K + ((size_t)(b * SEQ + k0 + krow) * NKV + kv) * HD + kcol;
            bf16x8 k1 = *(const bf16x8*)(kptr);
            bf16x8 k2 = *(const bf16x8*)(kptr + 8);
            *(bf16x8*)(&Ks[krow * 136 + kcol]) = k1;
            *(bf16x8*)(&Ks[krow * 136 + kcol + 8]) = k2;

            const bf16* vptr = V + ((size_t)(b * SEQ + k0 + krow) * NKV + kv) * HD + kcol;
            bf16x8 v1 = *(const bf16x8*)(vptr);
            bf16x8 v2 = *(const bf16x8*)(vptr + 8);
            #pragma unroll
            for (int i = 0; i < 8; i++) Vt[(kcol + i) * 40 + krow] = v1[i];
            #pragma unroll
            for (int i = 0; i < 8; i++) Vt[(kcol + 8 + i) * 40 + krow] = v2[i];
        }
        __syncthreads();

        if (k0 <= qw + 15) {   // tile has at least one unmasked key for this wave
            // ---- QK^T: scores[16 q][32 keys] ----
            floatx4 s0 = {0.f, 0.f, 0.f, 0.f};
            floatx4 s1 = {0.f, 0.f, 0.f, 0.f};
            #pragma unroll
            for (int t = 0; t < 4; t++) {
                bf16x8 kf0 = *(const bf16x8*)(&Ks[c * 136 + quad * 8 + t * 32]);
                bf16x8 kf1 = *(const bf16x8*)(&Ks[(16 + c) * 136 + quad * 8 + t * 32]);
                s0 = __builtin_amdgcn_mfma_f32_16x16x32_bf16(qf[t], kf0, s0, 0, 0, 0);
                s1 = __builtin_amdgcn_mfma_f32_16x16x32_bf16(qf[t], kf1, s1, 0, 0, 0);
            }

            // ---- online softmax (row = qw + quad*4 + r, cols c / c+16) ----
            float p0[4], p1[4], al[4];
            #pragma unroll
            for (int r = 0; r < 4; r++) {
                const int qrow = qw + quad * 4 + r;
                float v0 = s0[r] * scale;
                float v1s = s1[r] * scale;
                if (k0 + c > qrow)      v0  = -INFINITY;
                if (k0 + 16 + c > qrow) v1s = -INFINITY;
                float mx = fmaxf(v0, v1s);
                #pragma unroll
                for (int msk = 8; msk; msk >>= 1) mx = fmaxf(mx, __shfl_xor(mx, msk));
                float newm = fmaxf(m_r[r], mx);
                al[r] = __expf(m_r[r] - newm);
                m_r[r] = newm;
                p0[r] = __expf(v0 - newm);
                p1[r] = __expf(v1s - newm);
                float rs = p0[r] + p1[r];
                #pragma unroll
                for (int msk = 8; msk; msk >>= 1) rs += __shfl_xor(rs, msk);
                l_r[r] = l_r[r] * al[r] + rs;
            }
            #pragma unroll
            for (int f = 0; f < 8; f++)
                #pragma unroll
                for (int r = 0; r < 4; r++) o_acc[f][r] *= al[r];

            // ---- P (C-layout) -> LDS -> A-layout (wave-local round trip) ----
            #pragma unroll
            for (int r = 0; r < 4; r++) {
                psw[(quad * 4 + r) * 40 + c]      = (bf16)p0[r];
                psw[(quad * 4 + r) * 40 + 16 + c] = (bf16)p1[r];
            }
            // wave-uniform branch -> scalar wait is legal; guarantees the
            // ds_writes above are complete before the ds_read below
            asm volatile("s_waitcnt lgkmcnt(0)" ::: "memory");
            bf16x8 pf = *(const bf16x8*)(&psw[c * 40 + quad * 8]);

            // ---- PV: O[16 q][128 d] += P[16][32] * V[32][128] ----
            #pragma unroll
            for (int f = 0; f < 8; f++) {
                bf16x8 vf = *(const bf16x8*)(&Vt[(f * 16 + c) * 40 + quad * 8]);
                o_acc[f] = __builtin_amdgcn_mfma_f32_16x16x32_bf16(pf, vf, o_acc[f], 0, 0, 0);
            }
        }
        __syncthreads();
    }

    // ---- epilogue: normalize and store ----
    #pragma unroll
    for (int r = 0; r < 4; r++) {
        const float inv = 1.0f / l_r[r];
        const int qrow = qw + quad * 4 + r;
        bf16* op = O + ((size_t)(b * SEQ + qrow) * NH + h) * HD;
        #pragma unroll
        for (int f = 0; f < 8; f++) op[f * 16 + c] = (bf16)(o_acc[f][r] * inv);
    }
}

// ---------------------------------------------------------------------------
extern "C" void kernel_launch(void* const* d_in, const int* in_sizes, int n_in,
                              void* d_out, int out_size, void* d_ws, size_t ws_size,
                              hipStream_t stream)
{
    const float* x   = (const float*)d_in[0];
    const float* pe  = (const float*)d_in[1];
    const float* qw  = (const float*)d_in[2];
    const float* kw  = (const float*)d_in[3];
    const float* vw  = (const float*)d_in[4];
    const float* ow  = (const float*)d_in[5];
    const float* qnw = (const float*)d_in[6];
    const float* knw = (const float*)d_in[7];
    float* out = (float*)d_out;

    bf16* qb = (bf16*)d_ws;                               // [B,S,NH,HD]  bf16
    bf16* kb = qb + (size_t)BATCH * SEQ * NH * HD;        // [B,S,NKV,HD] bf16
    bf16* vb = kb + (size_t)BATCH * SEQ * NKV * HD;       // [B,S,NKV,HD] bf16
    bf16* ab = vb + (size_t)BATCH * SEQ * NKV * HD;       // [B,S,NH,HD]  bf16

    const int M = BATCH * SEQ;

    gemm_bt<float, bf16><<<dim3(M / 64, (NH * HD) / 64), 256, 0, stream>>>(qb, x, qw, M, NH * HD, HID);
    gemm_bt<float, bf16><<<dim3(M / 64, (NKV * HD) / 64), 256, 0, stream>>>(kb, x, kw, M, NKV * HD, HID);
    gemm_bt<float, bf16><<<dim3(M / 64, (NKV * HD) / 64), 256, 0, stream>>>(vb, x, vw, M, NKV * HD, HID);

    norm_rope<<<dim3(SEQ, NH + NKV, BATCH), 128, 0, stream>>>(qb, kb, pe, qnw, knw);

    fattn<<<dim3(SEQ / 64, NH, BATCH), 256, 0, stream>>>(ab, qb, kb, vb);

    gemm_bt<bf16, float><<<dim3(M / 64, HID / 64), 256, 0, stream>>>(out, ab, ow, M, HID, NH * HD);
}

// Round 3
// 588.035 us; speedup vs baseline: 1.3638x; 1.3638x over previous
//
#include <hip/hip_runtime.h>
#include <hip/hip_bf16.h>

#define BATCH 2
#define SEQ   2048
#define HID   2048
#define NH    16
#define NKV   8
#define HD    128

typedef __bf16 bf16;
typedef bf16  bf16x8  __attribute__((ext_vector_type(8)));
typedef bf16  bf16x4  __attribute__((ext_vector_type(4)));
typedef float floatx4 __attribute__((ext_vector_type(4)));

typedef __attribute__((address_space(3))) void lds_void;
typedef const __attribute__((address_space(1))) void gmem_void;

__device__ inline void async16(const void* g, void* l) {
    __builtin_amdgcn_global_load_lds((gmem_void*)g, (lds_void*)l, 16, 0, 0);
}

// ---------------------------------------------------------------------------
// f32 -> bf16 bulk convert (memory-bound)
// ---------------------------------------------------------------------------
__global__ __launch_bounds__(256) void cvt(bf16* __restrict__ dst,
                                           const float* __restrict__ src, int n)
{
    int i = (blockIdx.x * 256 + threadIdx.x) * 8;
    if (i >= n) return;
    const float4* p = (const float4*)(src + i);
    float4 u0 = p[0], u1 = p[1];
    bf16x8 v;
    v[0] = (bf16)u0.x; v[1] = (bf16)u0.y; v[2] = (bf16)u0.z; v[3] = (bf16)u0.w;
    v[4] = (bf16)u1.x; v[5] = (bf16)u1.y; v[6] = (bf16)u1.z; v[7] = (bf16)u1.w;
    *(bf16x8*)(dst + i) = v;
}

// ---------------------------------------------------------------------------
// GEMM  C = A[M,K] * W[N,K]^T, 128x128 tile, BK=32, m97 structure.
// AMODE: 0 = A f32 row-major (manual cvt stage)
//        1 = A bf16 row-major (global_load_lds)
//        2 = A bf16 head-major [B][K/128][2048][128] (global_load_lds)
// WMODE: 0 = W f32 (manual cvt)   1 = W bf16 (global_load_lds)
// CMODE: 0 = C f32 row-major      1 = C bf16 head-major [B][N/128][2048][128]
//        2 = C bf16 transposed    [B][N][2048]   (V^T)
// ---------------------------------------------------------------------------
template <int AMODE, int WMODE, int CMODE>
__global__ __launch_bounds__(256) void gemm128(void* __restrict__ Cp,
                                               const void* __restrict__ Ap,
                                               const void* __restrict__ Wp,
                                               int M, int N, int K)
{
    __shared__ bf16 As[128 * 32];
    __shared__ bf16 Ws[128 * 32];

    const int tid  = threadIdx.x;
    const int wv   = tid >> 6;
    const int lane = tid & 63;
    const int quad = lane >> 4;
    const int c    = lane & 15;

    const int m0 = blockIdx.x * 128;
    const int n0 = blockIdx.y * 128;
    const int wm = (wv >> 1) * 64;
    const int wn = (wv & 1) * 64;

    const int arow = lane >> 2;        // async: row within 16-row chunk
    const int acol = (lane & 3) * 8;   // async: elem offset in BK

    floatx4 acc[4][4] = {};

    for (int k0 = 0; k0 < K; k0 += 32) {
        // ---- stage A tile (128 x 32) ----
        if constexpr (AMODE == 0) {
            const float* A = (const float*)Ap;
            #pragma unroll
            for (int it = 0; it < 2; it++) {
                int row = it * 64 + (tid >> 2);
                int col = (tid & 3) * 8;
                const float4* p = (const float4*)(A + (size_t)(m0 + row) * K + k0 + col);
                float4 u0 = p[0], u1 = p[1];
                bf16x8 v;
                v[0] = (bf16)u0.x; v[1] = (bf16)u0.y; v[2] = (bf16)u0.z; v[3] = (bf16)u0.w;
                v[4] = (bf16)u1.x; v[5] = (bf16)u1.y; v[6] = (bf16)u1.z; v[7] = (bf16)u1.w;
                *(bf16x8*)(&As[row * 32 + col]) = v;
            }
        } else {
            const bf16* A = (const bf16*)Ap;
            #pragma unroll
            for (int ch = 0; ch < 2; ch++) {
                int row = wv * 32 + ch * 16 + arow;
                const bf16* g;
                if constexpr (AMODE == 1) {
                    g = A + (size_t)(m0 + row) * K + k0 + acol;
                } else {   // head-major: [B][K>>7][2048][128]
                    int m = m0 + row;
                    g = A + (((size_t)(m >> 11) * (K >> 7) + (k0 >> 7)) * 2048 + (m & 2047)) * 128
                          + (k0 & 127) + acol;
                }
                async16(g, &As[(wv * 32 + ch * 16) * 32]);
            }
        }
        // ---- stage W tile (128 x 32) ----
        if constexpr (WMODE == 0) {
            const float* W = (const float*)Wp;
            #pragma unroll
            for (int it = 0; it < 2; it++) {
                int row = it * 64 + (tid >> 2);
                int col = (tid & 3) * 8;
                const float4* p = (const float4*)(W + (size_t)(n0 + row) * K + k0 + col);
                float4 u0 = p[0], u1 = p[1];
                bf16x8 v;
                v[0] = (bf16)u0.x; v[1] = (bf16)u0.y; v[2] = (bf16)u0.z; v[3] = (bf16)u0.w;
                v[4] = (bf16)u1.x; v[5] = (bf16)u1.y; v[6] = (bf16)u1.z; v[7] = (bf16)u1.w;
                *(bf16x8*)(&Ws[row * 32 + col]) = v;
            }
        } else {
            const bf16* W = (const bf16*)Wp;
            #pragma unroll
            for (int ch = 0; ch < 2; ch++) {
                int row = wv * 32 + ch * 16 + arow;
                const bf16* g = W + (size_t)(n0 + row) * K + k0 + acol;
                async16(g, &Ws[(wv * 32 + ch * 16) * 32]);
            }
        }
        __syncthreads();

        bf16x8 af[4], bw[4];
        #pragma unroll
        for (int i = 0; i < 4; i++) af[i] = *(const bf16x8*)(&As[(wm + i * 16 + c) * 32 + quad * 8]);
        #pragma unroll
        for (int j = 0; j < 4; j++) bw[j] = *(const bf16x8*)(&Ws[(wn + j * 16 + c) * 32 + quad * 8]);
        #pragma unroll
        for (int i = 0; i < 4; i++)
            #pragma unroll
            for (int j = 0; j < 4; j++)
                acc[i][j] = __builtin_amdgcn_mfma_f32_16x16x32_bf16(af[i], bw[j], acc[i][j], 0, 0, 0);
        __syncthreads();
    }

    // ---- epilogue.  C/D layout: col = lane&15, row = quad*4+reg ----
    if constexpr (CMODE == 0) {
        float* C = (float*)Cp;
        #pragma unroll
        for (int i = 0; i < 4; i++)
            #pragma unroll
            for (int j = 0; j < 4; j++)
                #pragma unroll
                for (int r = 0; r < 4; r++) {
                    int m = m0 + wm + i * 16 + quad * 4 + r;
                    int n = n0 + wn + j * 16 + c;
                    C[(size_t)m * N + n] = acc[i][j][r];
                }
    } else if constexpr (CMODE == 1) {
        bf16* C = (bf16*)Cp;
        const int b = m0 >> 11;
        #pragma unroll
        for (int j = 0; j < 4; j++) {
            int n = n0 + wn + j * 16 + c;
            size_t base = ((size_t)(b * (N >> 7) + (n >> 7)) * 2048) * 128 + (n & 127);
            #pragma unroll
            for (int i = 0; i < 4; i++)
                #pragma unroll
                for (int r = 0; r < 4; r++) {
                    int s = (m0 & 2047) + wm + i * 16 + quad * 4 + r;
                    C[base + (size_t)s * 128] = (bf16)acc[i][j][r];
                }
        }
    } else {   // CMODE 2: V^T  [B][N][2048]
        bf16* C = (bf16*)Cp;
        const int b = m0 >> 11;
        #pragma unroll
        for (int j = 0; j < 4; j++) {
            int n = n0 + wn + j * 16 + c;
            size_t base = ((size_t)b * N + n) * 2048;
            #pragma unroll
            for (int i = 0; i < 4; i++) {
                int s0 = (m0 & 2047) + wm + i * 16 + quad * 4;
                bf16x4 v;
                #pragma unroll
                for (int r = 0; r < 4; r++) v[r] = (bf16)acc[i][j][r];
                *(bf16x4*)(&C[base + s0]) = v;
            }
        }
    }
}

// ---------------------------------------------------------------------------
// RMSNorm(D=128) + RoPE, in place on head-major bf16 q/k.
// grid = (SEQ, NH+NKV, BATCH), block = 128
// ---------------------------------------------------------------------------
__global__ __launch_bounds__(128) void norm_rope(bf16* __restrict__ q,
                                                 bf16* __restrict__ k,
                                                 const float* __restrict__ pe,
                                                 const float* __restrict__ qnw,
                                                 const float* __restrict__ knw)
{
    const int s  = blockIdx.x;
    const int hh = blockIdx.y;
    const int b  = blockIdx.z;
    const int d  = threadIdx.x;

    bf16* buf;
    const float* w;
    if (hh < NH) {
        buf = q + ((size_t)(b * NH + hh) * SEQ + s) * HD;
        w = qnw;
    } else {
        buf = k + ((size_t)(b * NKV + (hh - NH)) * SEQ + s) * HD;
        w = knw;
    }

    float x = (float)buf[d];
    float ss = x * x;
    #pragma unroll
    for (int m = 32; m; m >>= 1) ss += __shfl_xor(ss, m);

    __shared__ float red[2];
    __shared__ float nv[128];
    if ((d & 63) == 0) red[d >> 6] = ss;
    __syncthreads();
    float var = (red[0] + red[1]) * (1.0f / 128.0f);
    float nx = x * rsqrtf(var + 1e-6f) * w[d];
    nv[d] = nx;
    __syncthreads();

    const float* pev = pe + ((size_t)b * SEQ + s) * HD;
    float o;
    if (d < 64) {
        o = nx * pev[d] - nv[d + 64] * pev[64 + d];
    } else {
        o = nv[d - 64] * pev[d] + nx * pev[d - 64];
    }
    buf[d] = (bf16)o;
}

// ---------------------------------------------------------------------------
// Flash attention, causal, GQA rep=2.  Head-major Q/K, global V^T.
// block = 4 waves; wave w owns 16 q-rows; K-tile = 64 keys.
// Heavy blocks first: qblk = gridDim.x-1-blockIdx.x.
// ---------------------------------------------------------------------------
__global__ __launch_bounds__(256) void fattn(bf16* __restrict__ O,
                                             const bf16* __restrict__ Q,
                                             const bf16* __restrict__ Kh,
                                             const bf16* __restrict__ Vtg)
{
    const int qblk = (int)gridDim.x - 1 - (int)blockIdx.x;
    const int h    = blockIdx.y;
    const int b    = blockIdx.z;
    const int kv   = h >> 1;

    const int tid  = threadIdx.x;
    const int wv   = tid >> 6;
    const int lane = tid & 63;
    const int quad = lane >> 4;
    const int c    = lane & 15;

    __shared__ bf16 Ks[64 * 136];     // [key][d]
    __shared__ bf16 Vs[128 * 72];     // [d][key]
    __shared__ bf16 Ps[4 * 16 * 72];  // per-wave P

    const int qw = qblk * 64 + wv * 16;

    bf16x8 qf[4];
    {
        const bf16* qp = Q + ((size_t)(b * NH + h) * SEQ + qw + c) * HD + quad * 8;
        #pragma unroll
        for (int t = 0; t < 4; t++) qf[t] = *(const bf16x8*)(qp + t * 32);
    }

    floatx4 o_acc[8] = {};
    float m_r[4], l_r[4];
    #pragma unroll
    for (int r = 0; r < 4; r++) { m_r[r] = -INFINITY; l_r[r] = 0.0f; }

    const bf16* kbase = Kh  + (size_t)(b * NKV + kv) * SEQ * HD;
    const bf16* vbase = Vtg + (size_t)(b * NKV + kv) * HD * SEQ;

    const int kr  = tid >> 2, ksc = (tid & 3) * 32;   // K staging
    const int vd  = tid >> 1, vkc = (tid & 1) * 32;   // V^T staging
    bf16* psw = &Ps[wv * 16 * 72];
    const int nkt = qblk + 1;
    const float scale = 0.08838834764831845f;

    for (int kt = 0; kt < nkt; kt++) {
        const int k0 = kt * 64;
        // ---- stage K[64][128] and V^T[128][64] (all vector, padded strides) ----
        {
            const bf16* kp = kbase + (size_t)(k0 + kr) * HD + ksc;
            #pragma unroll
            for (int i = 0; i < 4; i++)
                *(bf16x8*)(&Ks[kr * 136 + ksc + i * 8]) = *(const bf16x8*)(kp + i * 8);
            const bf16* vp = vbase + (size_t)vd * SEQ + k0 + vkc;
            #pragma unroll
            for (int i = 0; i < 4; i++)
                *(bf16x8*)(&Vs[vd * 72 + vkc + i * 8]) = *(const bf16x8*)(vp + i * 8);
        }
        __syncthreads();

        // ---- QK^T: 16 q-rows x 64 keys ----
        floatx4 sc4[4] = {};
        #pragma unroll
        for (int t = 0; t < 4; t++) {
            #pragma unroll
            for (int g = 0; g < 4; g++) {
                bf16x8 kf = *(const bf16x8*)(&Ks[(g * 16 + c) * 136 + t * 32 + quad * 8]);
                sc4[g] = __builtin_amdgcn_mfma_f32_16x16x32_bf16(qf[t], kf, sc4[g], 0, 0, 0);
            }
        }

        // ---- online softmax ----
        const bool last = (kt == nkt - 1);
        float al[4];
        #pragma unroll
        for (int r = 0; r < 4; r++) {
            const int qrow = qw + quad * 4 + r;
            float v[4];
            #pragma unroll
            for (int g = 0; g < 4; g++) {
                v[g] = sc4[g][r] * scale;
                if (last && (k0 + g * 16 + c > qrow)) v[g] = -INFINITY;
            }
            float mx = fmaxf(fmaxf(v[0], v[1]), fmaxf(v[2], v[3]));
            #pragma unroll
            for (int msk = 8; msk; msk >>= 1) mx = fmaxf(mx, __shfl_xor(mx, msk));
            float newm = fmaxf(m_r[r], mx);
            al[r] = __expf(m_r[r] - newm);
            m_r[r] = newm;
            float rs = 0.0f;
            #pragma unroll
            for (int g = 0; g < 4; g++) { v[g] = __expf(v[g] - newm); rs += v[g]; }
            #pragma unroll
            for (int msk = 8; msk; msk >>= 1) rs += __shfl_xor(rs, msk);
            l_r[r] = l_r[r] * al[r] + rs;
            #pragma unroll
            for (int g = 0; g < 4; g++) psw[(quad * 4 + r) * 72 + g * 16 + c] = (bf16)v[g];
        }
        #pragma unroll
        for (int f = 0; f < 8; f++)
            #pragma unroll
            for (int r = 0; r < 4; r++) o_acc[f][r] *= al[r];

        // wave-local LDS round trip: drain ds_writes before ds_read
        asm volatile("s_waitcnt lgkmcnt(0)" ::: "memory");
        bf16x8 pf0 = *(const bf16x8*)(&psw[c * 72 + quad * 8]);
        bf16x8 pf1 = *(const bf16x8*)(&psw[c * 72 + 32 + quad * 8]);

        // ---- PV ----
        #pragma unroll
        for (int f = 0; f < 8; f++) {
            bf16x8 vf0 = *(const bf16x8*)(&Vs[(f * 16 + c) * 72 + quad * 8]);
            bf16x8 vf1 = *(const bf16x8*)(&Vs[(f * 16 + c) * 72 + 32 + quad * 8]);
            o_acc[f] = __builtin_amdgcn_mfma_f32_16x16x32_bf16(pf0, vf0, o_acc[f], 0, 0, 0);
            o_acc[f] = __builtin_amdgcn_mfma_f32_16x16x32_bf16(pf1, vf1, o_acc[f], 0, 0, 0);
        }
        __syncthreads();
    }

    // ---- epilogue ----
    #pragma unroll
    for (int r = 0; r < 4; r++) {
        const float inv = 1.0f / l_r[r];
        const int qrow = qw + quad * 4 + r;
        bf16* op = O + ((size_t)(b * NH + h) * SEQ + qrow) * HD;
        #pragma unroll
        for (int f = 0; f < 8; f++) op[f * 16 + c] = (bf16)(o_acc[f][r] * inv);
    }
}

// ---------------------------------------------------------------------------
extern "C" void kernel_launch(void* const* d_in, const int* in_sizes, int n_in,
                              void* d_out, int out_size, void* d_ws, size_t ws_size,
                              hipStream_t stream)
{
    const float* x   = (const float*)d_in[0];
    const float* pe  = (const float*)d_in[1];
    const float* qw  = (const float*)d_in[2];
    const float* kw  = (const float*)d_in[3];
    const float* vw  = (const float*)d_in[4];
    const float* ow  = (const float*)d_in[5];
    const float* qnw = (const float*)d_in[6];
    const float* knw = (const float*)d_in[7];
    float* out = (float*)d_out;

    const size_t XN = 8388608, QWN = 4194304, KWN = 2097152, VWN = 2097152, OWN = 4194304;

    bf16* qb = (bf16*)d_ws;          // [B][NH][S][HD]   head-major
    bf16* kb = qb + XN;              // [B][NKV][S][HD]  head-major
    bf16* vt = kb + KWN * 2;         // [B][NKV][HD][S]  V^T   (4.2M elems)
    bf16* ab = vt + VWN * 2;         // [B][NH][S][HD]   head-major
    bf16* cvt_base = ab + XN;

    const bool fit = ws_size >= (size_t)92274688;
    const int M = BATCH * SEQ;

    if (fit) {
        bf16* xb  = cvt_base;
        bf16* qwb = xb  + XN;
        bf16* kwb = qwb + QWN;
        bf16* vwb = kwb + KWN;
        bf16* owb = vwb + VWN;
        cvt<<<XN  / 8 / 256, 256, 0, stream>>>(xb,  x,  (int)XN);
        cvt<<<QWN / 8 / 256, 256, 0, stream>>>(qwb, qw, (int)QWN);
        cvt<<<KWN / 8 / 256, 256, 0, stream>>>(kwb, kw, (int)KWN);
        cvt<<<VWN / 8 / 256, 256, 0, stream>>>(vwb, vw, (int)VWN);
        cvt<<<OWN / 8 / 256, 256, 0, stream>>>(owb, ow, (int)OWN);

        gemm128<1, 1, 1><<<dim3(32, 16), 256, 0, stream>>>(qb, xb, qwb, M, 2048, 2048);
        gemm128<1, 1, 1><<<dim3(32,  8), 256, 0, stream>>>(kb, xb, kwb, M, 1024, 2048);
        gemm128<1, 1, 2><<<dim3(32,  8), 256, 0, stream>>>(vt, xb, vwb, M, 1024, 2048);

        norm_rope<<<dim3(SEQ, NH + NKV, BATCH), 128, 0, stream>>>(qb, kb, pe, qnw, knw);
        fattn<<<dim3(SEQ / 64, NH, BATCH), 256, 0, stream>>>(ab, qb, kb, vt);

        gemm128<2, 1, 0><<<dim3(32, 16), 256, 0, stream>>>(out, ab, owb, M, 2048, 2048);
    } else {
        gemm128<0, 0, 1><<<dim3(32, 16), 256, 0, stream>>>(qb, x, qw, M, 2048, 2048);
        gemm128<0, 0, 1><<<dim3(32,  8), 256, 0, stream>>>(kb, x, kw, M, 1024, 2048);
        gemm128<0, 0, 2><<<dim3(32,  8), 256, 0, stream>>>(vt, x, vw, M, 1024, 2048);

        norm_rope<<<dim3(SEQ, NH + NKV, BATCH), 128, 0, stream>>>(qb, kb, pe, qnw, knw);
        fattn<<<dim3(SEQ / 64, NH, BATCH), 256, 0, stream>>>(ab, qb, kb, vt);

        gemm128<2, 0, 0><<<dim3(32, 16), 256, 0, stream>>>(out, ab, ow, M, 2048, 2048);
    }
}